// Round 4
// baseline (2699.283 us; speedup 1.0000x reference)
//
#include <hip/hip_runtime.h>

// Problem constants (match reference)
#define NB 512   // batch
#define NT 512   // time
#define NI 128   // input dim  (K_x, 4 k-tiles)
#define NH 256   // hidden dim (K_h, 8 k-tiles)
#define NG 1024  // 4*NH gate rows
#define NMT 8    // m-tiles of 16 per wave (8 waves * 8 * 16 = 1024 rows)
#define NWAVE 8
#define EPSV 1e-5f

// W_hh frag f=(w*8+m)*8+kt  at Wf8[f*64+l]          (512 frags, 512 KB)
// W_ih frag g=(w*8+m)*4+kx  at Wf8[32768 + g*64+l]  (256 frags, 256 KB)
#define WXOFF 32768
#define GXOFF_BYTES (1u << 20)   // gxall at +1 MB in workspace

typedef short short8 __attribute__((ext_vector_type(8)));  // 8 bf16 = MFMA A/B frag
typedef float f32x4 __attribute__((ext_vector_type(4)));   // MFMA C/D frag

__device__ __forceinline__ unsigned short f32_to_bf16(float f) {
  unsigned int u = __float_as_uint(f);
  u += 0x7fffu + ((u >> 16) & 1u);   // round-to-nearest-even
  return (unsigned short)(u >> 16);
}
__device__ __forceinline__ float bf16_to_f32(unsigned short u) {
  return __uint_as_float(((unsigned int)u) << 16);
}
__device__ __forceinline__ void gload_lds16(const void* g, void* l) {
  __builtin_amdgcn_global_load_lds(
      (const __attribute__((address_space(1))) unsigned int*)g,
      (__attribute__((address_space(3))) unsigned int*)l, 16, 0, 0);
}

// ---------------------------------------------------------------------------
// Prep 1: W_hh and W_ih in MFMA A-fragment order, bf16 (unchanged).
// ---------------------------------------------------------------------------
__global__ void prep_kernel(const float* __restrict__ W_ih, const float* __restrict__ W_hh,
                            const float* __restrict__ b_ih, const float* __restrict__ b_hh,
                            unsigned short* __restrict__ Wf, float* __restrict__ bsum) {
  int o = blockIdx.x * blockDim.x + threadIdx.x;   // over (512+256)*512 elements
  int e = o & 7;
  int l = (o >> 3) & 63;
  int f = o >> 9;
  if (f < 512) {              // W_hh frags
    int kt = f & 7, m = (f >> 3) & 7, w = f >> 6;
    int row = w * 128 + m * 16 + (l & 15);
    int k = kt * 32 + ((l >> 4) << 3) + e;
    Wf[o] = f32_to_bf16(W_hh[row * NH + k]);
  } else if (f < 768) {       // W_ih frags
    int g = f - 512;
    int kx = g & 3, m = (g >> 2) & 7, w = g >> 5;
    int row = w * 128 + m * 16 + (l & 15);
    int k = kx * 32 + ((l >> 4) << 3) + e;
    Wf[o] = f32_to_bf16(W_ih[row * NI + k]);
  }
  if (o < NG) bsum[o] = b_ih[o] + b_hh[o];
}

// ---------------------------------------------------------------------------
// Prep 2: rank-sort sequences by length (descending) -> perm (unchanged).
// ---------------------------------------------------------------------------
__global__ void sort_kernel(const int* __restrict__ lengths, int* __restrict__ perm) {
  int i = threadIdx.x;
  __shared__ int L[NB];
  int li = lengths[i];
  L[i] = li;
  __syncthreads();
  int r = 0;
  for (int k = 0; k < NB; ++k) {
    int lk = L[k];
    r += (lk > li) || (lk == li && k < i);
  }
  perm[r] = i;
}

// ---------------------------------------------------------------------------
// Pre-GEMM: gxall[b][t][g] = bf16( X[b][t] . W_ih[g] + bsum[g] ).
// Grid (T/64, B), 512 threads.  Wave w owns gate rows w*128..+127.
// Per 16-t tile: build B frags from X, 32 MFMA/wave, +bias, round to bf16
// into a padded LDS tile, then coalesced 16B stores to gxall.
// ---------------------------------------------------------------------------
__global__ __launch_bounds__(512, 2)
void gemm_xproj(const float* __restrict__ X, const short8* __restrict__ Wf8,
                const float* __restrict__ bsum, unsigned short* __restrict__ gxall) {
  const int b = blockIdx.y;
  const int t0 = blockIdx.x * 64;
  const int tid = threadIdx.x;
  const int w = tid >> 6, l = tid & 63;
  __shared__ __align__(16) unsigned short tile[16][1032];   // +8 pad: kills 16-way conflict

  short8 wi[NMT][4];
#pragma unroll
  for (int m = 0; m < NMT; ++m)
#pragma unroll
    for (int kx = 0; kx < 4; ++kx)
      wi[m][kx] = Wf8[WXOFF + ((w * 8 + m) * 4 + kx) * 64 + l];

  const int c = l & 15, kg = l >> 4;
  for (int nt = 0; nt < 4; ++nt) {
    const float* xrow = X + ((size_t)b * NT + t0 + nt * 16 + c) * NI + kg * 8;
    f32x4 acc[NMT];
#pragma unroll
    for (int m = 0; m < NMT; ++m) acc[m] = (f32x4){0.f, 0.f, 0.f, 0.f};
#pragma unroll
    for (int kx = 0; kx < 4; ++kx) {
      float4 xa = *(const float4*)(xrow + kx * 32);
      float4 xc = *(const float4*)(xrow + kx * 32 + 4);
      short8 bx;
      bx[0] = (short)f32_to_bf16(xa.x); bx[1] = (short)f32_to_bf16(xa.y);
      bx[2] = (short)f32_to_bf16(xa.z); bx[3] = (short)f32_to_bf16(xa.w);
      bx[4] = (short)f32_to_bf16(xc.x); bx[5] = (short)f32_to_bf16(xc.y);
      bx[6] = (short)f32_to_bf16(xc.z); bx[7] = (short)f32_to_bf16(xc.w);
#pragma unroll
      for (int m = 0; m < NMT; ++m)
        acc[m] = __builtin_amdgcn_mfma_f32_16x16x32_bf16(wi[m][kx], bx, acc[m], 0, 0, 0);
    }
#pragma unroll
    for (int m = 0; m < NMT; ++m) {
      int rb = w * 128 + m * 16 + kg * 4;
      f32x4 bv = *(const f32x4*)&bsum[rb];
      ushort4 pk;
      pk.x = f32_to_bf16(acc[m][0] + bv[0]); pk.y = f32_to_bf16(acc[m][1] + bv[1]);
      pk.z = f32_to_bf16(acc[m][2] + bv[2]); pk.w = f32_to_bf16(acc[m][3] + bv[3]);
      *(ushort4*)&tile[c][rb] = pk;
    }
    __syncthreads();
    {
      unsigned short* dst = gxall + ((size_t)b * NT + t0 + nt * 16) * NG;
#pragma unroll
      for (int rep = 0; rep < 4; ++rep) {
        int r = (tid >> 7) + rep * 4;
        int col = (tid & 127) * 8;
        *(uint4*)&dst[(size_t)r * NG + col] = *(const uint4*)&tile[r][col];
      }
    }
    __syncthreads();
  }
}

// ---------------------------------------------------------------------------
// Main (primary): one block (512 thr = 8 waves) per PAIR of sorted sequences.
// W_hh residency: kt0-4 VGPR (160 regs), kt5-6 LDS (128 KB), kt7 streamed
// (64 KB/step, L2-hot; issued in two 4-frag groups to cap in-flight regs).
// x-projections come precomputed from gxall, staged into a 4-slot LDS ring
// via global_load_lds issued 3 steps ahead (HBM latency hidden by barriers).
// No X access, no chunk phase, no bsum in the loop -> no spill pressure.
// ---------------------------------------------------------------------------
__global__ __launch_bounds__(512, 2)
void lstm_ln_pre(const int* __restrict__ lengths, const int* __restrict__ perm,
                 const short8* __restrict__ Wf8, const unsigned short* __restrict__ gxall,
                 const float* __restrict__ gamma, const float* __restrict__ beta,
                 float* __restrict__ out) {
  const int p = blockIdx.x;
  const int tid = threadIdx.x;
  const int w = tid >> 6;      // wave 0..7
  const int l = tid & 63;      // lane

  __shared__ short8 ldsW[NWAVE * 16 * 64];                       // 128 KB: kt5,kt6
  __shared__ __align__(16) unsigned short gstage[4][2][NG];      // 16 KB ring
  __shared__ __align__(16) float gh[2][NG];                      // 8 KB
  __shared__ __align__(16) unsigned short hbuf[2][NH];           // 1 KB
  __shared__ float red[20];

  const int b0 = perm[2 * p];
  const int b1 = perm[2 * p + 1];
  const int len0 = lengths[b0];
  const int len1 = lengths[b1];
  const int lmax = (len0 > len1) ? len0 : len1;

  // ---- resident W_hh: kt0-4 in VGPR, kt5-6 into LDS ----
  short8 wreg[NMT][5];
#pragma unroll
  for (int m = 0; m < NMT; ++m)
#pragma unroll
    for (int kt = 0; kt < 5; ++kt)
      wreg[m][kt] = Wf8[((w * 8 + m) * 8 + kt) * 64 + l];
#pragma unroll
  for (int m = 0; m < NMT; ++m) {
    ldsW[(w * 16 + m) * 64 + l]     = Wf8[((w * 8 + m) * 8 + 5) * 64 + l];
    ldsW[(w * 16 + 8 + m) * 64 + l] = Wf8[((w * 8 + m) * 8 + 6) * 64 + l];
  }

  const int s = tid >> 8;       // 0: seq0, 1: seq1
  const int j = tid & 255;      // hidden unit
  const int mylen = s ? len1 : len0;
  float c = 0.f, h = 0.f;
  hbuf[s][j] = 0;

  auto stage = [&](int t2) {    // waves 0-3 DMA one 1KB quarter each
    if (w < 4) {
      int t2c = (t2 < NT) ? t2 : NT - 1;
      const unsigned short* gp = gxall
          + ((size_t)(w >= 2 ? b1 : b0) * NT + t2c) * NG + (w & 1) * 512 + (size_t)l * 8;
      gload_lds16(gp, &gstage[t2 & 3][w >> 1][(w & 1) * 512]);
    }
  };
  stage(0); stage(1); stage(2);
  __syncthreads();              // ldsW + hbuf + staged slots 0-2 visible

  const int seqb = l & 1;       // B col -> seq (cols replicate mod 2)
  const int kg = l >> 4;        // k-group within k-tile

  for (int t = 0; t < lmax; ++t) {
    stage(t + 3);               // prefetch ring slot (t+3)&3

    f32x4 acc[NMT];
#pragma unroll
    for (int m = 0; m < NMT; ++m) acc[m] = (f32x4){0.f, 0.f, 0.f, 0.f};

#pragma unroll
    for (int kt = 0; kt < 5; ++kt) {
      short8 bh = *(const short8*)&hbuf[seqb][kt * 32 + kg * 8];
#pragma unroll
      for (int m = 0; m < NMT; ++m)
        acc[m] = __builtin_amdgcn_mfma_f32_16x16x32_bf16(wreg[m][kt], bh, acc[m], 0, 0, 0);
    }
    // stream kt7 group A while kt5 (LDS) runs
    short8 swA[4];
#pragma unroll
    for (int m = 0; m < 4; ++m) swA[m] = Wf8[((w * 8 + m) * 8 + 7) * 64 + l];
    {
      short8 bh = *(const short8*)&hbuf[seqb][5 * 32 + kg * 8];
#pragma unroll
      for (int m = 0; m < NMT; ++m)
        acc[m] = __builtin_amdgcn_mfma_f32_16x16x32_bf16(ldsW[(w * 16 + m) * 64 + l], bh,
                                                         acc[m], 0, 0, 0);
    }
    short8 bh7 = *(const short8*)&hbuf[seqb][7 * 32 + kg * 8];
#pragma unroll
    for (int m = 0; m < 4; ++m)
      acc[m] = __builtin_amdgcn_mfma_f32_16x16x32_bf16(swA[m], bh7, acc[m], 0, 0, 0);
    // stream kt7 group B while kt6 (LDS) runs
    short8 swB[4];
#pragma unroll
    for (int m = 0; m < 4; ++m) swB[m] = Wf8[((w * 8 + 4 + m) * 8 + 7) * 64 + l];
    {
      short8 bh = *(const short8*)&hbuf[seqb][6 * 32 + kg * 8];
#pragma unroll
      for (int m = 0; m < NMT; ++m)
        acc[m] = __builtin_amdgcn_mfma_f32_16x16x32_bf16(ldsW[(w * 16 + 8 + m) * 64 + l], bh,
                                                         acc[m], 0, 0, 0);
    }
#pragma unroll
    for (int m = 0; m < 4; ++m)
      acc[4 + m] = __builtin_amdgcn_mfma_f32_16x16x32_bf16(swB[m], bh7, acc[4 + m], 0, 0, 0);

    // D layout: lane l, reg r -> row (l>>4)*4 + r, col l&15.  Cols 0/1 = seqs.
    if ((l & 15) < 2) {
#pragma unroll
      for (int m = 0; m < NMT; ++m)
        *(f32x4*)&gh[l & 1][w * 128 + m * 16 + kg * 4] = acc[m];
    }
    __syncthreads();

    // ---------------- pointwise cell update (biases inside gstage) ----------------
    {
      const unsigned short* gs = &gstage[t & 3][s][0];
      float pi = gh[s][j]          + bf16_to_f32(gs[j]);
      float pf = gh[s][NH + j]     + bf16_to_f32(gs[NH + j]);
      float pg = gh[s][2 * NH + j] + bf16_to_f32(gs[2 * NH + j]);
      float po = gh[s][3 * NH + j] + bf16_to_f32(gs[3 * NH + j]);
      if (t < mylen) {
        float ig = 1.f / (1.f + __expf(-pi));
        float fg = 1.f / (1.f + __expf(-pf));
        float gv = 1.f - 2.f / (1.f + __expf(2.f * pg));
        float og = 1.f / (1.f + __expf(-po));
        c = fg * c + ig * gv;
        h = og * (1.f - 2.f / (1.f + __expf(2.f * c)));
        hbuf[s][j] = f32_to_bf16(h);
      }
    }
    __syncthreads();
  }

  // ---- LayerNorm over H=256 per sequence ----
  float sum = h, sq = h * h;
#pragma unroll
  for (int off = 32; off > 0; off >>= 1) {
    sum += __shfl_xor(sum, off);
    sq  += __shfl_xor(sq, off);
  }
  if (l == 0) { red[w] = sum; red[8 + w] = sq; }
  __syncthreads();
  if (tid == 0) {
    float S = red[0] + red[1] + red[2] + red[3];
    float Q = red[8] + red[9] + red[10] + red[11];
    float mu = S * (1.f / NH);
    red[16] = mu;
    red[17] = rsqrtf(Q * (1.f / NH) - mu * mu + EPSV);
  }
  if (tid == 256) {
    float S = red[4] + red[5] + red[6] + red[7];
    float Q = red[12] + red[13] + red[14] + red[15];
    float mu = S * (1.f / NH);
    red[18] = mu;
    red[19] = rsqrtf(Q * (1.f / NH) - mu * mu + EPSV);
  }
  __syncthreads();
  {
    float mu = red[16 + 2 * s], rstd = red[17 + 2 * s];
    int b = s ? b1 : b0;
    out[(size_t)b * NH + j] = (h - mu) * rstd * gamma[j] + beta[j];
  }
}

// ---------------------------------------------------------------------------
// Fallback (workspace too small for gxall): round-3 kernel verbatim.
// ---------------------------------------------------------------------------
__global__ __launch_bounds__(512, 2)
void lstm_ln_chunk(const float* __restrict__ X, const int* __restrict__ lengths,
                   const int* __restrict__ perm,
                   const short8* __restrict__ Wf8, const float* __restrict__ bsum,
                   const float* __restrict__ gamma, const float* __restrict__ beta,
                   float* __restrict__ out) {
  const int p = blockIdx.x;
  const int tid = threadIdx.x;
  const int w = tid >> 6;
  const int l = tid & 63;

  __shared__ short8 ldsW[NWAVE * 14 * 64];
  __shared__ __align__(16) unsigned short gx[16][NG];
  __shared__ __align__(16) float gh[2][NG];
  __shared__ __align__(16) unsigned short hbuf[2][NH];
  __shared__ float red[20];

  const int b0 = perm[2 * p];
  const int b1 = perm[2 * p + 1];
  const int len0 = lengths[b0];
  const int len1 = lengths[b1];
  const int lmax = (len0 > len1) ? len0 : len1;

  short8 wreg[NMT][5];
#pragma unroll
  for (int m = 0; m < NMT; ++m)
#pragma unroll
    for (int kt = 0; kt < 5; ++kt)
      wreg[m][kt] = Wf8[((w * 8 + m) * 8 + kt) * 64 + l];
  short8 w6a = Wf8[((w * 8 + 6) * 8 + 6) * 64 + l];
  short8 w6b = Wf8[((w * 8 + 7) * 8 + 6) * 64 + l];
#pragma unroll
  for (int m = 0; m < NMT; ++m)
    ldsW[(w * 14 + m) * 64 + l] = Wf8[((w * 8 + m) * 8 + 5) * 64 + l];
#pragma unroll
  for (int m = 0; m < 6; ++m)
    ldsW[(w * 14 + 8 + m) * 64 + l] = Wf8[((w * 8 + m) * 8 + 6) * 64 + l];

  const int s = tid >> 8;
  const int j = tid & 255;
  const int mylen = s ? len1 : len0;
  const float bsi = bsum[j], bsf = bsum[NH + j], bsg = bsum[2 * NH + j], bso = bsum[3 * NH + j];
  float c = 0.f, h = 0.f;

  const float* __restrict__ xr0 = X + (size_t)b0 * NT * NI;
  const float* __restrict__ xr1 = X + (size_t)b1 * NT * NI;
  const int seqb = l & 1;
  const int kg = l >> 4;
  const int st = (l >> 1) & 7;
  const float* __restrict__ xp = seqb ? xr1 : xr0;

  hbuf[s][j] = 0;
  __syncthreads();

  for (int t = 0; t < lmax; ++t) {
    if ((t & 7) == 0) {
      const float* xb = xp + (size_t)(t + st) * NI + kg * 8;
      const int cc = l & 15;
#pragma unroll
      for (int half = 0; half < 2; ++half) {
        f32x4 ax[4];
#pragma unroll
        for (int m = 0; m < 4; ++m) ax[m] = (f32x4){0.f, 0.f, 0.f, 0.f};
#pragma unroll
        for (int kx = 0; kx < 4; ++kx) {
          float4 xa = *(const float4*)(xb + kx * 32);
          float4 xc = *(const float4*)(xb + kx * 32 + 4);
          short8 bx;
          bx[0] = (short)f32_to_bf16(xa.x); bx[1] = (short)f32_to_bf16(xa.y);
          bx[2] = (short)f32_to_bf16(xa.z); bx[3] = (short)f32_to_bf16(xa.w);
          bx[4] = (short)f32_to_bf16(xc.x); bx[5] = (short)f32_to_bf16(xc.y);
          bx[6] = (short)f32_to_bf16(xc.z); bx[7] = (short)f32_to_bf16(xc.w);
#pragma unroll
          for (int m = 0; m < 4; ++m) {
            short8 wi = Wf8[WXOFF + ((w * 8 + half * 4 + m) * 4 + kx) * 64 + l];
            ax[m] = __builtin_amdgcn_mfma_f32_16x16x32_bf16(wi, bx, ax[m], 0, 0, 0);
          }
        }
#pragma unroll
        for (int m = 0; m < 4; ++m) {
          int r0 = w * 128 + (half * 4 + m) * 16 + kg * 4;
          ushort4 pk;
          pk.x = f32_to_bf16(ax[m][0]); pk.y = f32_to_bf16(ax[m][1]);
          pk.z = f32_to_bf16(ax[m][2]); pk.w = f32_to_bf16(ax[m][3]);
          *(ushort4*)&gx[cc][r0] = pk;
        }
      }
    }

    f32x4 acc[NMT];
#pragma unroll
    for (int m = 0; m < NMT; ++m) acc[m] = (f32x4){0.f, 0.f, 0.f, 0.f};
#pragma unroll
    for (int kt = 0; kt < 5; ++kt) {
      short8 bh = *(const short8*)&hbuf[seqb][kt * 32 + kg * 8];
#pragma unroll
      for (int m = 0; m < NMT; ++m)
        acc[m] = __builtin_amdgcn_mfma_f32_16x16x32_bf16(wreg[m][kt], bh, acc[m], 0, 0, 0);
    }
    short8 sw[NMT];
#pragma unroll
    for (int m = 0; m < 4; ++m)
      sw[m] = Wf8[((w * 8 + m) * 8 + 7) * 64 + l];
    {
      short8 bh = *(const short8*)&hbuf[seqb][5 * 32 + kg * 8];
#pragma unroll
      for (int m = 0; m < NMT; ++m)
        acc[m] = __builtin_amdgcn_mfma_f32_16x16x32_bf16(ldsW[(w * 14 + m) * 64 + l], bh,
                                                         acc[m], 0, 0, 0);
    }
    short8 bh7 = *(const short8*)&hbuf[seqb][7 * 32 + kg * 8];
#pragma unroll
    for (int m = 0; m < 4; ++m)
      acc[m] = __builtin_amdgcn_mfma_f32_16x16x32_bf16(sw[m], bh7, acc[m], 0, 0, 0);
#pragma unroll
    for (int m = 4; m < 8; ++m)
      sw[m] = Wf8[((w * 8 + m) * 8 + 7) * 64 + l];
    {
      short8 bh = *(const short8*)&hbuf[seqb][6 * 32 + kg * 8];
#pragma unroll
      for (int m = 0; m < 6; ++m)
        acc[m] = __builtin_amdgcn_mfma_f32_16x16x32_bf16(ldsW[(w * 14 + 8 + m) * 64 + l], bh,
                                                         acc[m], 0, 0, 0);
      acc[6] = __builtin_amdgcn_mfma_f32_16x16x32_bf16(w6a, bh, acc[6], 0, 0, 0);
      acc[7] = __builtin_amdgcn_mfma_f32_16x16x32_bf16(w6b, bh, acc[7], 0, 0, 0);
    }
#pragma unroll
    for (int m = 4; m < 8; ++m)
      acc[m] = __builtin_amdgcn_mfma_f32_16x16x32_bf16(sw[m], bh7, acc[m], 0, 0, 0);

    if ((l & 15) < 2) {
#pragma unroll
      for (int m = 0; m < NMT; ++m)
        *(f32x4*)&gh[l & 1][w * 128 + m * 16 + kg * 4] = acc[m];
    }
    __syncthreads();

    {
      const int dt = ((t & 7) << 1) + s;
      float pi = gh[s][j]          + bf16_to_f32(gx[dt][j])          + bsi;
      float pf = gh[s][NH + j]     + bf16_to_f32(gx[dt][NH + j])     + bsf;
      float pg = gh[s][2 * NH + j] + bf16_to_f32(gx[dt][2 * NH + j]) + bsg;
      float po = gh[s][3 * NH + j] + bf16_to_f32(gx[dt][3 * NH + j]) + bso;
      if (t < mylen) {
        float ig = 1.f / (1.f + __expf(-pi));
        float fg = 1.f / (1.f + __expf(-pf));
        float gv = 1.f - 2.f / (1.f + __expf(2.f * pg));
        float og = 1.f / (1.f + __expf(-po));
        c = fg * c + ig * gv;
        h = og * (1.f - 2.f / (1.f + __expf(2.f * c)));
        hbuf[s][j] = f32_to_bf16(h);
      }
    }
    __syncthreads();
  }

  float sum = h, sq = h * h;
#pragma unroll
  for (int off = 32; off > 0; off >>= 1) {
    sum += __shfl_xor(sum, off);
    sq  += __shfl_xor(sq, off);
  }
  if (l == 0) { red[w] = sum; red[8 + w] = sq; }
  __syncthreads();
  if (tid == 0) {
    float S = red[0] + red[1] + red[2] + red[3];
    float Q = red[8] + red[9] + red[10] + red[11];
    float mu = S * (1.f / NH);
    red[16] = mu;
    red[17] = rsqrtf(Q * (1.f / NH) - mu * mu + EPSV);
  }
  if (tid == 256) {
    float S = red[4] + red[5] + red[6] + red[7];
    float Q = red[12] + red[13] + red[14] + red[15];
    float mu = S * (1.f / NH);
    red[18] = mu;
    red[19] = rsqrtf(Q * (1.f / NH) - mu * mu + EPSV);
  }
  __syncthreads();
  {
    float mu = red[16 + 2 * s], rstd = red[17 + 2 * s];
    int b = s ? b1 : b0;
    out[(size_t)b * NH + j] = (h - mu) * rstd * gamma[j] + beta[j];
  }
}

extern "C" void kernel_launch(void* const* d_in, const int* in_sizes, int n_in,
                              void* d_out, int out_size, void* d_ws, size_t ws_size,
                              hipStream_t stream) {
  const float* X       = (const float*)d_in[0];
  const int*   lengths = (const int*)d_in[1];
  const float* W_ih    = (const float*)d_in[2];
  const float* W_hh    = (const float*)d_in[3];
  const float* b_ih    = (const float*)d_in[4];
  const float* b_hh    = (const float*)d_in[5];
  const float* gamma   = (const float*)d_in[6];
  const float* beta    = (const float*)d_in[7];
  float* out = (float*)d_out;

  unsigned short* Wf = (unsigned short*)d_ws;                                      // 768 KB
  float* bsum = (float*)((char*)d_ws + (size_t)768 * 512 * sizeof(unsigned short));// 4 KB
  int* perm = (int*)((char*)bsum + NG * sizeof(float));                            // 2 KB
  unsigned short* gxall = (unsigned short*)((char*)d_ws + GXOFF_BYTES);            // 512 MB

  int total = 768 * 512;
  prep_kernel<<<(total + 255) / 256, 256, 0, stream>>>(W_ih, W_hh, b_ih, b_hh, Wf, bsum);
  sort_kernel<<<1, NB, 0, stream>>>(lengths, perm);

  size_t need = (size_t)GXOFF_BYTES + (size_t)NB * NT * NG * sizeof(unsigned short);
  if (ws_size >= need) {
    gemm_xproj<<<dim3(NT / 64, NB), 512, 0, stream>>>(X, (const short8*)Wf, bsum, gxall);
    lstm_ln_pre<<<NB / 2, 512, 0, stream>>>(lengths, perm, (const short8*)Wf, gxall,
                                            gamma, beta, out);
  } else {
    lstm_ln_chunk<<<NB / 2, 512, 0, stream>>>(X, lengths, perm, (const short8*)Wf, bsum,
                                              gamma, beta, out);
  }
}

// Round 5
// 2687.128 us; speedup vs baseline: 1.0045x; 1.0045x over previous
//
#include <hip/hip_runtime.h>

// Problem constants (match reference)
#define NB 512   // batch
#define NT 512   // time
#define NI 128   // input dim  (K_x, 4 k-tiles)
#define NH 256   // hidden dim (K_h, 8 k-tiles)
#define NG 1024  // 4*NH gate rows
#define NMT 8    // m-tiles of 16 per wave (8 waves * 8 * 16 = 1024 rows)
#define NWAVE 8
#define CH 8     // chunk = 8 time steps of x-projection per pass
#define EPSV 1e-5f

// W_hh frag f=(w*8+m)*8+kt  at Wf8[f*64+l]          (512 frags, 512 KB)
// W_ih frag g=(w*8+m)*4+kx  at Wf8[32768 + g*64+l]  (256 frags, 256 KB)
#define WXOFF 32768

typedef short short8 __attribute__((ext_vector_type(8)));  // 8 bf16 = MFMA A/B frag
typedef float f32x4 __attribute__((ext_vector_type(4)));   // MFMA C/D frag

__device__ __forceinline__ unsigned short f32_to_bf16(float f) {
  unsigned int u = __float_as_uint(f);
  u += 0x7fffu + ((u >> 16) & 1u);   // round-to-nearest-even
  return (unsigned short)(u >> 16);
}
__device__ __forceinline__ float bf16_to_f32(unsigned short u) {
  return __uint_as_float(((unsigned int)u) << 16);
}

// ---------------------------------------------------------------------------
// Prep 1: W_hh and W_ih in MFMA A-fragment order, bf16.
// Fragment: lane l holds 8 contiguous-k bf16 of row = w*128+m*16+(l&15),
// k = kt*32 + (l>>4)*8 + e.  Same (lane-group,e)->k convention used for the
// B operand, so the MFMA result is invariant to HW internal k ordering.
// ---------------------------------------------------------------------------
__global__ void prep_kernel(const float* __restrict__ W_ih, const float* __restrict__ W_hh,
                            const float* __restrict__ b_ih, const float* __restrict__ b_hh,
                            unsigned short* __restrict__ Wf, float* __restrict__ bsum) {
  int o = blockIdx.x * blockDim.x + threadIdx.x;   // over (512+256)*512 elements
  int e = o & 7;
  int l = (o >> 3) & 63;
  int f = o >> 9;
  if (f < 512) {              // W_hh frags
    int kt = f & 7, m = (f >> 3) & 7, w = f >> 6;
    int row = w * 128 + m * 16 + (l & 15);
    int k = kt * 32 + ((l >> 4) << 3) + e;
    Wf[o] = f32_to_bf16(W_hh[row * NH + k]);
  } else if (f < 768) {       // W_ih frags
    int g = f - 512;
    int kx = g & 3, m = (g >> 2) & 7, w = g >> 5;
    int row = w * 128 + m * 16 + (l & 15);
    int k = kx * 32 + ((l >> 4) << 3) + e;
    Wf[o] = f32_to_bf16(W_ih[row * NI + k]);
  }
  if (o < NG) bsum[o] = b_ih[o] + b_hh[o];
}

// ---------------------------------------------------------------------------
// Prep 2: rank-sort sequences by length (descending) -> perm.
// ---------------------------------------------------------------------------
__global__ void sort_kernel(const int* __restrict__ lengths, int* __restrict__ perm) {
  int i = threadIdx.x;
  __shared__ int L[NB];
  int li = lengths[i];
  L[i] = li;
  __syncthreads();
  int r = 0;
  for (int k = 0; k < NB; ++k) {
    int lk = L[k];
    r += (lk > li) || (lk == li && k < i);
  }
  perm[r] = i;
}

// ---------------------------------------------------------------------------
// Main: one block (512 thr = 8 waves) per PAIR of sorted sequences.
// W_hh residency: kt0-4 VGPR (160 regs), kt5 + kt6(m0-5) LDS (112 KB),
// kt6(m6,7) VGPR, kt7 streamed (64 KB/step, L2-hot).
// Every CH=8 steps: x-proj chunk GEMM (two m-halves to cap VGPR pressure),
// N=16 cols = (step,seq); W_ih streamed once per chunk (256 KB, L2-hot);
// result parked bf16 in LDS gx[16][1024].
// Per step: gh = W_hh @ h (64 MFMA/wave); pointwise by (s=tid>>8, j=tid&255),
// c,h in fp32 registers; packed-sequence freeze semantics preserved.
//
// __launch_bounds__(512, 1): 1 block/CU -> 2 waves/SIMD -> 256 VGPR cap.
// (512, 2) was interpreted CUDA-style as 2 blocks/CU -> 128 VGPR cap, which
// spilled the 160-reg wreg[] every step (48 MB scratch writes, r3/r4 PMC).
// ---------------------------------------------------------------------------
__global__ __launch_bounds__(512, 1)
void lstm_ln_kernel(const float* __restrict__ X, const int* __restrict__ lengths,
                    const int* __restrict__ perm,
                    const short8* __restrict__ Wf8, const float* __restrict__ bsum,
                    const float* __restrict__ gamma, const float* __restrict__ beta,
                    float* __restrict__ out) {
  const int p = blockIdx.x;
  const int tid = threadIdx.x;
  const int w = tid >> 6;      // wave 0..7
  const int l = tid & 63;      // lane

  __shared__ short8 ldsW[NWAVE * 14 * 64];                   // 112 KB W_hh frags
  __shared__ __align__(16) unsigned short gx[2 * CH][NG];    // 32 KB x-proj bf16
  __shared__ __align__(16) float gh[2][NG];                  // 8 KB h-proj fp32
  __shared__ __align__(16) unsigned short hbuf[2][NH];       // 1 KB h bf16
  __shared__ float red[20];

  const int b0 = perm[2 * p];
  const int b1 = perm[2 * p + 1];
  const int len0 = lengths[b0];
  const int len1 = lengths[b1];
  const int lmax = (len0 > len1) ? len0 : len1;

  // ---- load resident W_hh fragments ----
  short8 wreg[NMT][5];
#pragma unroll
  for (int m = 0; m < NMT; ++m)
#pragma unroll
    for (int kt = 0; kt < 5; ++kt)
      wreg[m][kt] = Wf8[((w * 8 + m) * 8 + kt) * 64 + l];
  short8 w6a = Wf8[((w * 8 + 6) * 8 + 6) * 64 + l];   // kt6, m=6
  short8 w6b = Wf8[((w * 8 + 7) * 8 + 6) * 64 + l];   // kt6, m=7
#pragma unroll
  for (int m = 0; m < NMT; ++m)
    ldsW[(w * 14 + m) * 64 + l] = Wf8[((w * 8 + m) * 8 + 5) * 64 + l];
#pragma unroll
  for (int m = 0; m < 6; ++m)
    ldsW[(w * 14 + 8 + m) * 64 + l] = Wf8[((w * 8 + m) * 8 + 6) * 64 + l];

  // ---- pointwise cell mapping ----
  const int s = tid >> 8;       // 0: seq0, 1: seq1
  const int j = tid & 255;      // hidden unit
  const int mylen = s ? len1 : len0;
  const float bsi = bsum[j], bsf = bsum[NH + j], bsg = bsum[2 * NH + j], bso = bsum[3 * NH + j];
  float c = 0.f, h = 0.f;

  const float* __restrict__ xr0 = X + (size_t)b0 * NT * NI;
  const float* __restrict__ xr1 = X + (size_t)b1 * NT * NI;
  const int seqb = l & 1;                 // B col -> seq (cols replicate mod 2)
  const int kg = l >> 4;                  // k-group within k-tile
  const int st = (l >> 1) & 7;            // chunk step for this lane's column
  const float* __restrict__ xp = seqb ? xr1 : xr0;

  hbuf[s][j] = 0;
  __syncthreads();

  for (int t = 0; t < lmax; ++t) {
    // -------- chunk: x-projection for steps t..t+7 (two m-halves) --------
    if ((t & 7) == 0) {
      // t + st <= 504 + 7 = 511 always in-bounds (lengths <= NT)
      const float* xb = xp + (size_t)(t + st) * NI + kg * 8;
      const int cc = l & 15;
#pragma unroll
      for (int half = 0; half < 2; ++half) {
        f32x4 ax[4];
#pragma unroll
        for (int m = 0; m < 4; ++m) ax[m] = (f32x4){0.f, 0.f, 0.f, 0.f};
#pragma unroll
        for (int kx = 0; kx < 4; ++kx) {
          float4 xa = *(const float4*)(xb + kx * 32);
          float4 xc = *(const float4*)(xb + kx * 32 + 4);
          short8 bx;
          bx[0] = (short)f32_to_bf16(xa.x); bx[1] = (short)f32_to_bf16(xa.y);
          bx[2] = (short)f32_to_bf16(xa.z); bx[3] = (short)f32_to_bf16(xa.w);
          bx[4] = (short)f32_to_bf16(xc.x); bx[5] = (short)f32_to_bf16(xc.y);
          bx[6] = (short)f32_to_bf16(xc.z); bx[7] = (short)f32_to_bf16(xc.w);
#pragma unroll
          for (int m = 0; m < 4; ++m) {
            short8 wi = Wf8[WXOFF + ((w * 8 + half * 4 + m) * 4 + kx) * 64 + l];
            ax[m] = __builtin_amdgcn_mfma_f32_16x16x32_bf16(wi, bx, ax[m], 0, 0, 0);
          }
        }
#pragma unroll
        for (int m = 0; m < 4; ++m) {
          int r0 = w * 128 + (half * 4 + m) * 16 + kg * 4;
          ushort4 pk;
          pk.x = f32_to_bf16(ax[m][0]); pk.y = f32_to_bf16(ax[m][1]);
          pk.z = f32_to_bf16(ax[m][2]); pk.w = f32_to_bf16(ax[m][3]);
          *(ushort4*)&gx[cc][r0] = pk;
        }
      }
      // gx reads happen only after this iteration's __syncthreads() below
    }

    // ---------------- recurrent GEMV: gh = W_hh @ h ----------------
    f32x4 acc[NMT];
#pragma unroll
    for (int m = 0; m < NMT; ++m) acc[m] = (f32x4){0.f, 0.f, 0.f, 0.f};

#pragma unroll
    for (int kt = 0; kt < 5; ++kt) {
      short8 bh = *(const short8*)&hbuf[seqb][kt * 32 + kg * 8];
#pragma unroll
      for (int m = 0; m < NMT; ++m)
        acc[m] = __builtin_amdgcn_mfma_f32_16x16x32_bf16(wreg[m][kt], bh, acc[m], 0, 0, 0);
    }
    // streamed kt7 loads issued in two halves to cap in-flight VGPRs
    short8 sw[NMT];
#pragma unroll
    for (int m = 0; m < 4; ++m)
      sw[m] = Wf8[((w * 8 + m) * 8 + 7) * 64 + l];
    {
      short8 bh = *(const short8*)&hbuf[seqb][5 * 32 + kg * 8];
#pragma unroll
      for (int m = 0; m < NMT; ++m)
        acc[m] = __builtin_amdgcn_mfma_f32_16x16x32_bf16(ldsW[(w * 14 + m) * 64 + l], bh,
                                                         acc[m], 0, 0, 0);
    }
    short8 bh7 = *(const short8*)&hbuf[seqb][7 * 32 + kg * 8];
#pragma unroll
    for (int m = 0; m < 4; ++m)
      acc[m] = __builtin_amdgcn_mfma_f32_16x16x32_bf16(sw[m], bh7, acc[m], 0, 0, 0);
#pragma unroll
    for (int m = 4; m < 8; ++m)
      sw[m] = Wf8[((w * 8 + m) * 8 + 7) * 64 + l];
    {
      short8 bh = *(const short8*)&hbuf[seqb][6 * 32 + kg * 8];
#pragma unroll
      for (int m = 0; m < 6; ++m)
        acc[m] = __builtin_amdgcn_mfma_f32_16x16x32_bf16(ldsW[(w * 14 + 8 + m) * 64 + l], bh,
                                                         acc[m], 0, 0, 0);
      acc[6] = __builtin_amdgcn_mfma_f32_16x16x32_bf16(w6a, bh, acc[6], 0, 0, 0);
      acc[7] = __builtin_amdgcn_mfma_f32_16x16x32_bf16(w6b, bh, acc[7], 0, 0, 0);
    }
#pragma unroll
    for (int m = 4; m < 8; ++m)
      acc[m] = __builtin_amdgcn_mfma_f32_16x16x32_bf16(sw[m], bh7, acc[m], 0, 0, 0);

    // D layout: lane l, reg r -> row (l>>4)*4 + r, col l&15.  Cols 0/1 = seqs.
    if ((l & 15) < 2) {
#pragma unroll
      for (int m = 0; m < NMT; ++m)
        *(f32x4*)&gh[l & 1][w * 128 + m * 16 + kg * 4] = acc[m];
    }
    __syncthreads();

    // ---------------- pointwise cell update ----------------
    {
      const int dt = ((t & 7) << 1) + s;
      float pi = gh[s][j]          + bf16_to_f32(gx[dt][j])          + bsi;
      float pf = gh[s][NH + j]     + bf16_to_f32(gx[dt][NH + j])     + bsf;
      float pg = gh[s][2 * NH + j] + bf16_to_f32(gx[dt][2 * NH + j]) + bsg;
      float po = gh[s][3 * NH + j] + bf16_to_f32(gx[dt][3 * NH + j]) + bso;
      if (t < mylen) {
        float ig = 1.f / (1.f + __expf(-pi));
        float fg = 1.f / (1.f + __expf(-pf));
        float gv = 1.f - 2.f / (1.f + __expf(2.f * pg));
        float og = 1.f / (1.f + __expf(-po));
        c = fg * c + ig * gv;
        h = og * (1.f - 2.f / (1.f + __expf(2.f * c)));
        hbuf[s][j] = f32_to_bf16(h);
      }
    }
    __syncthreads();
  }

  // ---- LayerNorm over H=256 per sequence (waves 0-3: seq0, 4-7: seq1) ----
  float sum = h, sq = h * h;
#pragma unroll
  for (int off = 32; off > 0; off >>= 1) {
    sum += __shfl_xor(sum, off);
    sq  += __shfl_xor(sq, off);
  }
  if (l == 0) { red[w] = sum; red[8 + w] = sq; }
  __syncthreads();
  if (tid == 0) {
    float S = red[0] + red[1] + red[2] + red[3];
    float Q = red[8] + red[9] + red[10] + red[11];
    float mu = S * (1.f / NH);
    red[16] = mu;
    red[17] = rsqrtf(Q * (1.f / NH) - mu * mu + EPSV);
  }
  if (tid == 256) {
    float S = red[4] + red[5] + red[6] + red[7];
    float Q = red[12] + red[13] + red[14] + red[15];
    float mu = S * (1.f / NH);
    red[18] = mu;
    red[19] = rsqrtf(Q * (1.f / NH) - mu * mu + EPSV);
  }
  __syncthreads();
  {
    float mu = red[16 + 2 * s], rstd = red[17 + 2 * s];
    int b = s ? b1 : b0;
    out[(size_t)b * NH + j] = (h - mu) * rstd * gamma[j] + beta[j];
  }
}

extern "C" void kernel_launch(void* const* d_in, const int* in_sizes, int n_in,
                              void* d_out, int out_size, void* d_ws, size_t ws_size,
                              hipStream_t stream) {
  const float* X       = (const float*)d_in[0];
  const int*   lengths = (const int*)d_in[1];
  const float* W_ih    = (const float*)d_in[2];
  const float* W_hh    = (const float*)d_in[3];
  const float* b_ih    = (const float*)d_in[4];
  const float* b_hh    = (const float*)d_in[5];
  const float* gamma   = (const float*)d_in[6];
  const float* beta    = (const float*)d_in[7];
  float* out = (float*)d_out;

  // workspace layout (768 KB weights + 4 KB bsum + 2 KB perm)
  unsigned short* Wf = (unsigned short*)d_ws;
  float* bsum = (float*)((char*)d_ws + (size_t)768 * 512 * sizeof(unsigned short));
  int* perm = (int*)((char*)bsum + NG * sizeof(float));

  int total = 768 * 512;   // (512 W_hh + 256 W_ih frags) * 512 elems
  prep_kernel<<<(total + 255) / 256, 256, 0, stream>>>(W_ih, W_hh, b_ih, b_hh, Wf, bsum);
  sort_kernel<<<1, NB, 0, stream>>>(lengths, perm);
  lstm_ln_kernel<<<NB / 2, 512, 0, stream>>>(X, lengths, perm, (const short8*)Wf, bsum,
                                             gamma, beta, out);
}

// Round 6
// 2684.773 us; speedup vs baseline: 1.0054x; 1.0009x over previous
//
#include <hip/hip_runtime.h>

// Problem constants (match reference)
#define NB 512   // batch
#define NT 512   // time
#define NI 128   // input dim  (K_x, 4 k-tiles)
#define NH 256   // hidden dim (K_h, 8 k-tiles)
#define NG 1024  // 4*NH gate rows
#define NMT 8    // m-tiles of 16 per wave (8 waves * 8 * 16 = 1024 rows)
#define NWAVE 8
#define CH 4     // chunk = 4 time steps of x-projection per pass
#define EPSV 1e-5f

// W_hh frag f=(w*8+m)*8+kt  at Wf8[f*64+l]          (512 frags, 512 KB)
// W_ih frag g=(w*8+m)*4+kx  at Wf8[32768 + g*64+l]  (256 frags, 256 KB)
#define WXOFF 32768

typedef short short8 __attribute__((ext_vector_type(8)));  // 8 bf16 = MFMA A/B frag
typedef float f32x4 __attribute__((ext_vector_type(4)));   // MFMA C/D frag

__device__ __forceinline__ unsigned short f32_to_bf16(float f) {
  unsigned int u = __float_as_uint(f);
  u += 0x7fffu + ((u >> 16) & 1u);   // round-to-nearest-even
  return (unsigned short)(u >> 16);
}
__device__ __forceinline__ float bf16_to_f32(unsigned short u) {
  return __uint_as_float(((unsigned int)u) << 16);
}

// ---------------------------------------------------------------------------
// Prep 1: W_hh and W_ih in MFMA A-fragment order, bf16 (unchanged layout).
// Fragment: lane l holds 8 contiguous-k bf16 of row = w*128+m*16+(l&15),
// k = kt*32 + (l>>4)*8 + e.  Same (lane-group,e)->k convention used for the
// B operand, so the MFMA result is invariant to HW internal k ordering.
// ---------------------------------------------------------------------------
__global__ void prep_kernel(const float* __restrict__ W_ih, const float* __restrict__ W_hh,
                            const float* __restrict__ b_ih, const float* __restrict__ b_hh,
                            unsigned short* __restrict__ Wf, float* __restrict__ bsum) {
  int o = blockIdx.x * blockDim.x + threadIdx.x;   // over (512+256)*512 elements
  int e = o & 7;
  int l = (o >> 3) & 63;
  int f = o >> 9;
  if (f < 512) {              // W_hh frags
    int kt = f & 7, m = (f >> 3) & 7, w = f >> 6;
    int row = w * 128 + m * 16 + (l & 15);
    int k = kt * 32 + ((l >> 4) << 3) + e;
    Wf[o] = f32_to_bf16(W_hh[row * NH + k]);
  } else if (f < 768) {       // W_ih frags
    int g = f - 512;
    int kx = g & 3, m = (g >> 2) & 7, w = g >> 5;
    int row = w * 128 + m * 16 + (l & 15);
    int k = kx * 32 + ((l >> 4) << 3) + e;
    Wf[o] = f32_to_bf16(W_ih[row * NI + k]);
  }
  if (o < NG) bsum[o] = b_ih[o] + b_hh[o];
}

// ---------------------------------------------------------------------------
// Prep 2: rank-sort sequences by length (descending) -> perm (unchanged).
// ---------------------------------------------------------------------------
__global__ void sort_kernel(const int* __restrict__ lengths, int* __restrict__ perm) {
  int i = threadIdx.x;
  __shared__ int L[NB];
  int li = lengths[i];
  L[i] = li;
  __syncthreads();
  int r = 0;
  for (int k = 0; k < NB; ++k) {
    int lk = L[k];
    r += (lk > li) || (lk == li && k < i);
  }
  perm[r] = i;
}

// ---------------------------------------------------------------------------
// Main: one block (512 thr = 8 waves) per PAIR of sorted sequences.
//
// Register budget (unified VGPR/AGPR file, 2 waves/SIMD = 256 total):
//   accum-side: wreg kt0-3 = 128 + acc 32 = 160
//   arch-side : stream group 32 + bh/addressing/pointwise ~30  => ~220 total.
// r1/r3/r5 all spilled (WRITE_SIZE 48-68 MB scratch) because the 5-kt
// partition demanded ~280; this 4-kt partition leaves ~36 regs of slack.
//
// W_hh residency: kt0-3 VGPR, kt4-5 LDS (128 KB), kt6-7 streamed from L2
// each step (128 KB/CU-step, hot) in two 8-frag groups interleaved with
// resident MFMAs to hide L2 latency.
// Every CH=4 steps: x-proj chunk GEMM (two m-halves), N=16 cols =
// (step 0-3) x (seq 0-1) (cols 8-15 replicas); bias folded in here; result
// parked bf16 in gx[8][NG+8] (padded: chunk store was a 16-way conflict).
// Per step: gh = W_hh @ h (64 MFMA/wave); pointwise by (s=tid>>8, j=tid&255),
// c,h in fp32 registers; packed-sequence freeze semantics preserved.
// ---------------------------------------------------------------------------
__global__ __launch_bounds__(512, 1)
void lstm_ln_kernel(const float* __restrict__ X, const int* __restrict__ lengths,
                    const int* __restrict__ perm,
                    const short8* __restrict__ Wf8, const float* __restrict__ bsum,
                    const float* __restrict__ gamma, const float* __restrict__ beta,
                    float* __restrict__ out) {
  const int p = blockIdx.x;
  const int tid = threadIdx.x;
  const int w = tid >> 6;      // wave 0..7
  const int l = tid & 63;      // lane

  __shared__ short8 ldsW[NWAVE * 16 * 64];                   // 128 KB: kt4 (f0-7), kt5 (f8-15)
  __shared__ __align__(16) unsigned short gx[2 * CH][NG + 8];// 16.1 KB x-proj bf16 (padded)
  __shared__ __align__(16) float gh[2][NG];                  // 8 KB h-proj fp32
  __shared__ __align__(16) unsigned short hbuf[2][NH];       // 1 KB h bf16
  __shared__ float red[20];

  const int b0 = perm[2 * p];
  const int b1 = perm[2 * p + 1];
  const int len0 = lengths[b0];
  const int len1 = lengths[b1];
  const int lmax = (len0 > len1) ? len0 : len1;

  // ---- resident W_hh: kt0-3 in VGPR, kt4-5 into LDS ----
  short8 wreg[NMT][4];
#pragma unroll
  for (int m = 0; m < NMT; ++m)
#pragma unroll
    for (int kt = 0; kt < 4; ++kt)
      wreg[m][kt] = Wf8[((w * 8 + m) * 8 + kt) * 64 + l];
#pragma unroll
  for (int m = 0; m < NMT; ++m) {
    ldsW[(w * 16 + m) * 64 + l]     = Wf8[((w * 8 + m) * 8 + 4) * 64 + l];
    ldsW[(w * 16 + 8 + m) * 64 + l] = Wf8[((w * 8 + m) * 8 + 5) * 64 + l];
  }

  // ---- pointwise cell mapping ----
  const int s = tid >> 8;       // 0: seq0, 1: seq1
  const int j = tid & 255;      // hidden unit
  const int mylen = s ? len1 : len0;
  float c = 0.f, h = 0.f;

  const float* __restrict__ xr0 = X + (size_t)b0 * NT * NI;
  const float* __restrict__ xr1 = X + (size_t)b1 * NT * NI;
  const int seqb = l & 1;                 // B col -> seq (cols replicate mod 2)
  const int kg = l >> 4;                  // k-group within k-tile
  const int st = (l >> 1) & 3;            // chunk step for this lane's column
  const float* __restrict__ xp = seqb ? xr1 : xr0;

  hbuf[s][j] = 0;
  __syncthreads();

  for (int t = 0; t < lmax; ++t) {
    // -------- chunk: x-projection for steps t..t+3 (two m-halves) --------
    if ((t & 3) == 0) {
      // t + st <= 508 + 3 = 511 always in-bounds (lengths <= NT)
      const float* xb = xp + (size_t)(t + st) * NI + kg * 8;
      const int cc = l & 15;
#pragma unroll
      for (int half = 0; half < 2; ++half) {
        f32x4 ax[4];
#pragma unroll
        for (int m = 0; m < 4; ++m) ax[m] = (f32x4){0.f, 0.f, 0.f, 0.f};
#pragma unroll
        for (int kx = 0; kx < 4; ++kx) {
          float4 xa = *(const float4*)(xb + kx * 32);
          float4 xc = *(const float4*)(xb + kx * 32 + 4);
          short8 bx;
          bx[0] = (short)f32_to_bf16(xa.x); bx[1] = (short)f32_to_bf16(xa.y);
          bx[2] = (short)f32_to_bf16(xa.z); bx[3] = (short)f32_to_bf16(xa.w);
          bx[4] = (short)f32_to_bf16(xc.x); bx[5] = (short)f32_to_bf16(xc.y);
          bx[6] = (short)f32_to_bf16(xc.z); bx[7] = (short)f32_to_bf16(xc.w);
#pragma unroll
          for (int m = 0; m < 4; ++m) {
            short8 wi = Wf8[WXOFF + ((w * 8 + half * 4 + m) * 4 + kx) * 64 + l];
            ax[m] = __builtin_amdgcn_mfma_f32_16x16x32_bf16(wi, bx, ax[m], 0, 0, 0);
          }
        }
        if (cc < 8) {       // cols 8-15 are replicas
#pragma unroll
          for (int m = 0; m < 4; ++m) {
            int r0 = w * 128 + (half * 4 + m) * 16 + kg * 4;
            f32x4 bv = *(const f32x4*)&bsum[r0];    // fold bias here
            ushort4 pk;
            pk.x = f32_to_bf16(ax[m][0] + bv[0]); pk.y = f32_to_bf16(ax[m][1] + bv[1]);
            pk.z = f32_to_bf16(ax[m][2] + bv[2]); pk.w = f32_to_bf16(ax[m][3] + bv[3]);
            *(ushort4*)&gx[cc][r0] = pk;
          }
        }
      }
      // gx reads happen only after this iteration's __syncthreads() below
    }

    // ---------------- recurrent GEMV: gh = W_hh @ h ----------------
    f32x4 acc[NMT];
#pragma unroll
    for (int m = 0; m < NMT; ++m) acc[m] = (f32x4){0.f, 0.f, 0.f, 0.f};

    // issue kt6 stream group (L2-hot); latency hides under kt0-2 MFMAs
    short8 swA[NMT];
#pragma unroll
    for (int m = 0; m < NMT; ++m) swA[m] = Wf8[((w * 8 + m) * 8 + 6) * 64 + l];

#pragma unroll
    for (int kt = 0; kt < 3; ++kt) {
      short8 bh = *(const short8*)&hbuf[seqb][kt * 32 + kg * 8];
#pragma unroll
      for (int m = 0; m < NMT; ++m)
        acc[m] = __builtin_amdgcn_mfma_f32_16x16x32_bf16(wreg[m][kt], bh, acc[m], 0, 0, 0);
    }
    // consume kt6; then issue kt7 group (hides under kt3/kt4/kt5)
    {
      short8 bh = *(const short8*)&hbuf[seqb][6 * 32 + kg * 8];
#pragma unroll
      for (int m = 0; m < NMT; ++m)
        acc[m] = __builtin_amdgcn_mfma_f32_16x16x32_bf16(swA[m], bh, acc[m], 0, 0, 0);
    }
    short8 swB[NMT];
#pragma unroll
    for (int m = 0; m < NMT; ++m) swB[m] = Wf8[((w * 8 + m) * 8 + 7) * 64 + l];
    {
      short8 bh = *(const short8*)&hbuf[seqb][3 * 32 + kg * 8];
#pragma unroll
      for (int m = 0; m < NMT; ++m)
        acc[m] = __builtin_amdgcn_mfma_f32_16x16x32_bf16(wreg[m][3], bh, acc[m], 0, 0, 0);
    }
    {
      short8 bh = *(const short8*)&hbuf[seqb][4 * 32 + kg * 8];
#pragma unroll
      for (int m = 0; m < NMT; ++m)
        acc[m] = __builtin_amdgcn_mfma_f32_16x16x32_bf16(ldsW[(w * 16 + m) * 64 + l], bh,
                                                         acc[m], 0, 0, 0);
    }
    {
      short8 bh = *(const short8*)&hbuf[seqb][5 * 32 + kg * 8];
#pragma unroll
      for (int m = 0; m < NMT; ++m)
        acc[m] = __builtin_amdgcn_mfma_f32_16x16x32_bf16(ldsW[(w * 16 + 8 + m) * 64 + l], bh,
                                                         acc[m], 0, 0, 0);
    }
    {
      short8 bh = *(const short8*)&hbuf[seqb][7 * 32 + kg * 8];
#pragma unroll
      for (int m = 0; m < NMT; ++m)
        acc[m] = __builtin_amdgcn_mfma_f32_16x16x32_bf16(swB[m], bh, acc[m], 0, 0, 0);
    }

    // D layout: lane l, reg r -> row (l>>4)*4 + r, col l&15.  Cols 0/1 = seqs.
    if ((l & 15) < 2) {
#pragma unroll
      for (int m = 0; m < NMT; ++m)
        *(f32x4*)&gh[l & 1][w * 128 + m * 16 + kg * 4] = acc[m];
    }
    __syncthreads();

    // ---------------- pointwise cell update (bias already in gx) ----------------
    {
      const int dt = ((t & 3) << 1) + s;
      float pi = gh[s][j]          + bf16_to_f32(gx[dt][j]);
      float pf = gh[s][NH + j]     + bf16_to_f32(gx[dt][NH + j]);
      float pg = gh[s][2 * NH + j] + bf16_to_f32(gx[dt][2 * NH + j]);
      float po = gh[s][3 * NH + j] + bf16_to_f32(gx[dt][3 * NH + j]);
      if (t < mylen) {
        float ig = 1.f / (1.f + __expf(-pi));
        float fg = 1.f / (1.f + __expf(-pf));
        float gv = 1.f - 2.f / (1.f + __expf(2.f * pg));
        float og = 1.f / (1.f + __expf(-po));
        c = fg * c + ig * gv;
        h = og * (1.f - 2.f / (1.f + __expf(2.f * c)));
        hbuf[s][j] = f32_to_bf16(h);
      }
    }
    __syncthreads();
  }

  // ---- LayerNorm over H=256 per sequence (waves 0-3: seq0, 4-7: seq1) ----
  float sum = h, sq = h * h;
#pragma unroll
  for (int off = 32; off > 0; off >>= 1) {
    sum += __shfl_xor(sum, off);
    sq  += __shfl_xor(sq, off);
  }
  if (l == 0) { red[w] = sum; red[8 + w] = sq; }
  __syncthreads();
  if (tid == 0) {
    float S = red[0] + red[1] + red[2] + red[3];
    float Q = red[8] + red[9] + red[10] + red[11];
    float mu = S * (1.f / NH);
    red[16] = mu;
    red[17] = rsqrtf(Q * (1.f / NH) - mu * mu + EPSV);
  }
  if (tid == 256) {
    float S = red[4] + red[5] + red[6] + red[7];
    float Q = red[12] + red[13] + red[14] + red[15];
    float mu = S * (1.f / NH);
    red[18] = mu;
    red[19] = rsqrtf(Q * (1.f / NH) - mu * mu + EPSV);
  }
  __syncthreads();
  {
    float mu = red[16 + 2 * s], rstd = red[17 + 2 * s];
    int b = s ? b1 : b0;
    out[(size_t)b * NH + j] = (h - mu) * rstd * gamma[j] + beta[j];
  }
}

extern "C" void kernel_launch(void* const* d_in, const int* in_sizes, int n_in,
                              void* d_out, int out_size, void* d_ws, size_t ws_size,
                              hipStream_t stream) {
  const float* X       = (const float*)d_in[0];
  const int*   lengths = (const int*)d_in[1];
  const float* W_ih    = (const float*)d_in[2];
  const float* W_hh    = (const float*)d_in[3];
  const float* b_ih    = (const float*)d_in[4];
  const float* b_hh    = (const float*)d_in[5];
  const float* gamma   = (const float*)d_in[6];
  const float* beta    = (const float*)d_in[7];
  float* out = (float*)d_out;

  // workspace layout (768 KB weights + 4 KB bsum + 2 KB perm)
  unsigned short* Wf = (unsigned short*)d_ws;
  float* bsum = (float*)((char*)d_ws + (size_t)768 * 512 * sizeof(unsigned short));
  int* perm = (int*)((char*)bsum + NG * sizeof(float));

  int total = 768 * 512;   // (512 W_hh + 256 W_ih frags) * 512 elems
  prep_kernel<<<(total + 255) / 256, 256, 0, stream>>>(W_ih, W_hh, b_ih, b_hh, Wf, bsum);
  sort_kernel<<<1, NB, 0, stream>>>(lengths, perm);
  lstm_ln_kernel<<<NB / 2, 512, 0, stream>>>(X, lengths, perm, (const short8*)Wf, bsum,
                                             gamma, beta, out);
}

// Round 7
// 2647.646 us; speedup vs baseline: 1.0195x; 1.0140x over previous
//
#include <hip/hip_runtime.h>

// Problem constants (match reference)
#define NB 512   // batch
#define NT 512   // time
#define NI 128   // input dim  (K_x, 4 k-tiles)
#define NH 256   // hidden dim (K_h, 8 k-tiles)
#define NG 1024  // 4*NH gate rows
#define NMT 8    // m-tiles of 16 per wave (8 waves * 8 * 16 = 1024 rows)
#define NWAVE 8
#define CH 4     // chunk = 4 time steps of x-projection per pass
#define EPSV 1e-5f

// W_hh frag f=(w*8+m)*8+kt  at Wf8[f*64+l]          (512 frags, 512 KB)
// W_ih frag g=(w*8+m)*4+kx  at Wf8[32768 + g*64+l]  (256 frags, 256 KB)
#define WXOFF 32768

typedef short short8 __attribute__((ext_vector_type(8)));  // 8 bf16 = MFMA A/B frag
typedef float f32x4 __attribute__((ext_vector_type(4)));   // MFMA C/D frag

__device__ __forceinline__ unsigned short f32_to_bf16(float f) {
  unsigned int u = __float_as_uint(f);
  u += 0x7fffu + ((u >> 16) & 1u);   // round-to-nearest-even
  return (unsigned short)(u >> 16);
}
__device__ __forceinline__ float bf16_to_f32(unsigned short u) {
  return __uint_as_float(((unsigned int)u) << 16);
}

// ---------------------------------------------------------------------------
// Prep 1: W_hh and W_ih in MFMA A-fragment order, bf16 (unchanged layout).
// Fragment: lane l holds 8 contiguous-k bf16 of row = w*128+m*16+(l&15),
// k = kt*32 + (l>>4)*8 + e.  Same (lane-group,e)->k convention used for the
// B operand, so the MFMA result is invariant to HW internal k ordering.
// ---------------------------------------------------------------------------
__global__ void prep_kernel(const float* __restrict__ W_ih, const float* __restrict__ W_hh,
                            const float* __restrict__ b_ih, const float* __restrict__ b_hh,
                            unsigned short* __restrict__ Wf, float* __restrict__ bsum) {
  int o = blockIdx.x * blockDim.x + threadIdx.x;   // over (512+256)*512 elements
  int e = o & 7;
  int l = (o >> 3) & 63;
  int f = o >> 9;
  if (f < 512) {              // W_hh frags
    int kt = f & 7, m = (f >> 3) & 7, w = f >> 6;
    int row = w * 128 + m * 16 + (l & 15);
    int k = kt * 32 + ((l >> 4) << 3) + e;
    Wf[o] = f32_to_bf16(W_hh[row * NH + k]);
  } else if (f < 768) {       // W_ih frags
    int g = f - 512;
    int kx = g & 3, m = (g >> 2) & 7, w = g >> 5;
    int row = w * 128 + m * 16 + (l & 15);
    int k = kx * 32 + ((l >> 4) << 3) + e;
    Wf[o] = f32_to_bf16(W_ih[row * NI + k]);
  }
  if (o < NG) bsum[o] = b_ih[o] + b_hh[o];
}

// ---------------------------------------------------------------------------
// Prep 2: rank-sort sequences by length (descending) -> perm (unchanged).
// ---------------------------------------------------------------------------
__global__ void sort_kernel(const int* __restrict__ lengths, int* __restrict__ perm) {
  int i = threadIdx.x;
  __shared__ int L[NB];
  int li = lengths[i];
  L[i] = li;
  __syncthreads();
  int r = 0;
  for (int k = 0; k < NB; ++k) {
    int lk = L[k];
    r += (lk > li) || (lk == li && k < i);
  }
  perm[r] = i;
}

// ---------------------------------------------------------------------------
// Main: one block (512 thr = 8 waves) per PAIR of sorted sequences.
//
// Register budget (unified VGPR/AGPR file, 2 waves/SIMD = 256 total/wave):
//   wreg kt0-2 = 96 + acc 32 = 128 accum-side
//   arch-side: at most 2 stream groups in flight (64) + bh/addr/misc ~35
//   => peak ~225, ~30 regs slack.  r3/r5/r6 all spilled (WRITE 33-49 MB
//   scratch): the 4-kt partition's true peak (with scheduler hoisting of
//   stream groups + chunk transients) exceeded 256.  One fewer resident
//   k-tile trades +64KB/step of L2-hot stream for zero spill-reload chains.
//
// W_hh residency: kt0-2 VGPR, kt3-4 LDS (128 KB), kt5-7 streamed from L2
// each step (192 KB/CU-step, hot) as three 8-frag groups, each issued one
// MFMA-block ahead of its consumption.
// Every CH=4 steps: x-proj chunk GEMM (two m-halves), bias folded in,
// result parked bf16 in gx[8][NG+8] (padded).
// Per step: gh = W @ h (64 MFMA/wave); pointwise by (s=tid>>8, j=tid&255),
// c,h in fp32 registers; packed-sequence freeze semantics preserved.
// ---------------------------------------------------------------------------
__global__ __launch_bounds__(512, 1)
void lstm_ln_kernel(const float* __restrict__ X, const int* __restrict__ lengths,
                    const int* __restrict__ perm,
                    const short8* __restrict__ Wf8, const float* __restrict__ bsum,
                    const float* __restrict__ gamma, const float* __restrict__ beta,
                    float* __restrict__ out) {
  const int p = blockIdx.x;
  const int tid = threadIdx.x;
  const int w = tid >> 6;      // wave 0..7
  const int l = tid & 63;      // lane

  __shared__ short8 ldsW[NWAVE * 16 * 64];                   // 128 KB: kt3 (f0-7), kt4 (f8-15)
  __shared__ __align__(16) unsigned short gx[2 * CH][NG + 8];// 16.1 KB x-proj bf16 (padded)
  __shared__ __align__(16) float gh[2][NG];                  // 8 KB h-proj fp32
  __shared__ __align__(16) unsigned short hbuf[2][NH];       // 1 KB h bf16
  __shared__ float red[20];

  const int b0 = perm[2 * p];
  const int b1 = perm[2 * p + 1];
  const int len0 = lengths[b0];
  const int len1 = lengths[b1];
  const int lmax = (len0 > len1) ? len0 : len1;

  // ---- resident W_hh: kt0-2 in VGPR, kt3-4 into LDS ----
  short8 wreg[NMT][3];
#pragma unroll
  for (int m = 0; m < NMT; ++m)
#pragma unroll
    for (int kt = 0; kt < 3; ++kt)
      wreg[m][kt] = Wf8[((w * 8 + m) * 8 + kt) * 64 + l];
#pragma unroll
  for (int m = 0; m < NMT; ++m) {
    ldsW[(w * 16 + m) * 64 + l]     = Wf8[((w * 8 + m) * 8 + 3) * 64 + l];
    ldsW[(w * 16 + 8 + m) * 64 + l] = Wf8[((w * 8 + m) * 8 + 4) * 64 + l];
  }

  // ---- pointwise cell mapping ----
  const int s = tid >> 8;       // 0: seq0, 1: seq1
  const int j = tid & 255;      // hidden unit
  const int mylen = s ? len1 : len0;
  float c = 0.f, h = 0.f;

  const float* __restrict__ xr0 = X + (size_t)b0 * NT * NI;
  const float* __restrict__ xr1 = X + (size_t)b1 * NT * NI;
  const int seqb = l & 1;                 // B col -> seq (cols replicate mod 2)
  const int kg = l >> 4;                  // k-group within k-tile
  const int st = (l >> 1) & 3;            // chunk step for this lane's column
  const float* __restrict__ xp = seqb ? xr1 : xr0;

  hbuf[s][j] = 0;
  __syncthreads();

  for (int t = 0; t < lmax; ++t) {
    // -------- chunk: x-projection for steps t..t+3 (two m-halves) --------
    if ((t & 3) == 0) {
      // t + st <= 508 + 3 = 511 always in-bounds (lengths <= NT)
      const float* xb = xp + (size_t)(t + st) * NI + kg * 8;
      const int cc = l & 15;
#pragma unroll
      for (int half = 0; half < 2; ++half) {
        f32x4 ax[4];
#pragma unroll
        for (int m = 0; m < 4; ++m) ax[m] = (f32x4){0.f, 0.f, 0.f, 0.f};
#pragma unroll
        for (int kx = 0; kx < 4; ++kx) {
          float4 xa = *(const float4*)(xb + kx * 32);
          float4 xc = *(const float4*)(xb + kx * 32 + 4);
          short8 bx;
          bx[0] = (short)f32_to_bf16(xa.x); bx[1] = (short)f32_to_bf16(xa.y);
          bx[2] = (short)f32_to_bf16(xa.z); bx[3] = (short)f32_to_bf16(xa.w);
          bx[4] = (short)f32_to_bf16(xc.x); bx[5] = (short)f32_to_bf16(xc.y);
          bx[6] = (short)f32_to_bf16(xc.z); bx[7] = (short)f32_to_bf16(xc.w);
#pragma unroll
          for (int m = 0; m < 4; ++m) {
            short8 wi = Wf8[WXOFF + ((w * 8 + half * 4 + m) * 4 + kx) * 64 + l];
            ax[m] = __builtin_amdgcn_mfma_f32_16x16x32_bf16(wi, bx, ax[m], 0, 0, 0);
          }
        }
        if (cc < 8) {       // cols 8-15 are replicas
#pragma unroll
          for (int m = 0; m < 4; ++m) {
            int r0 = w * 128 + (half * 4 + m) * 16 + kg * 4;
            f32x4 bv = *(const f32x4*)&bsum[r0];    // fold bias here
            ushort4 pk;
            pk.x = f32_to_bf16(ax[m][0] + bv[0]); pk.y = f32_to_bf16(ax[m][1] + bv[1]);
            pk.z = f32_to_bf16(ax[m][2] + bv[2]); pk.w = f32_to_bf16(ax[m][3] + bv[3]);
            *(ushort4*)&gx[cc][r0] = pk;
          }
        }
      }
      // gx reads happen only after this iteration's __syncthreads() below
    }

    // ---------------- recurrent GEMV: gh = W_hh @ h ----------------
    f32x4 acc[NMT];
#pragma unroll
    for (int m = 0; m < NMT; ++m) acc[m] = (f32x4){0.f, 0.f, 0.f, 0.f};

    // stream group A (kt5); lands while kt0-2 resident MFMAs run
    short8 swA[NMT];
#pragma unroll
    for (int m = 0; m < NMT; ++m) swA[m] = Wf8[((w * 8 + m) * 8 + 5) * 64 + l];

#pragma unroll
    for (int kt = 0; kt < 3; ++kt) {
      short8 bh = *(const short8*)&hbuf[seqb][kt * 32 + kg * 8];
#pragma unroll
      for (int m = 0; m < NMT; ++m)
        acc[m] = __builtin_amdgcn_mfma_f32_16x16x32_bf16(wreg[m][kt], bh, acc[m], 0, 0, 0);
    }
    // stream group B (kt6); lands while kt3 (LDS) + kt5 MFMAs run
    short8 swB[NMT];
#pragma unroll
    for (int m = 0; m < NMT; ++m) swB[m] = Wf8[((w * 8 + m) * 8 + 6) * 64 + l];
    {
      short8 bh = *(const short8*)&hbuf[seqb][3 * 32 + kg * 8];
#pragma unroll
      for (int m = 0; m < NMT; ++m)
        acc[m] = __builtin_amdgcn_mfma_f32_16x16x32_bf16(ldsW[(w * 16 + m) * 64 + l], bh,
                                                         acc[m], 0, 0, 0);
    }
    {
      short8 bh = *(const short8*)&hbuf[seqb][5 * 32 + kg * 8];
#pragma unroll
      for (int m = 0; m < NMT; ++m)
        acc[m] = __builtin_amdgcn_mfma_f32_16x16x32_bf16(swA[m], bh, acc[m], 0, 0, 0);
    }
    // stream group C (kt7); lands while kt4 (LDS) + kt6 MFMAs run
    short8 swC[NMT];
#pragma unroll
    for (int m = 0; m < NMT; ++m) swC[m] = Wf8[((w * 8 + m) * 8 + 7) * 64 + l];
    {
      short8 bh = *(const short8*)&hbuf[seqb][4 * 32 + kg * 8];
#pragma unroll
      for (int m = 0; m < NMT; ++m)
        acc[m] = __builtin_amdgcn_mfma_f32_16x16x32_bf16(ldsW[(w * 16 + 8 + m) * 64 + l], bh,
                                                         acc[m], 0, 0, 0);
    }
    {
      short8 bh = *(const short8*)&hbuf[seqb][6 * 32 + kg * 8];
#pragma unroll
      for (int m = 0; m < NMT; ++m)
        acc[m] = __builtin_amdgcn_mfma_f32_16x16x32_bf16(swB[m], bh, acc[m], 0, 0, 0);
    }
    {
      short8 bh = *(const short8*)&hbuf[seqb][7 * 32 + kg * 8];
#pragma unroll
      for (int m = 0; m < NMT; ++m)
        acc[m] = __builtin_amdgcn_mfma_f32_16x16x32_bf16(swC[m], bh, acc[m], 0, 0, 0);
    }

    // D layout: lane l, reg r -> row (l>>4)*4 + r, col l&15.  Cols 0/1 = seqs.
    if ((l & 15) < 2) {
#pragma unroll
      for (int m = 0; m < NMT; ++m)
        *(f32x4*)&gh[l & 1][w * 128 + m * 16 + kg * 4] = acc[m];
    }
    __syncthreads();

    // ---------------- pointwise cell update (bias already in gx) ----------------
    {
      const int dt = ((t & 3) << 1) + s;
      float pi = gh[s][j]          + bf16_to_f32(gx[dt][j]);
      float pf = gh[s][NH + j]     + bf16_to_f32(gx[dt][NH + j]);
      float pg = gh[s][2 * NH + j] + bf16_to_f32(gx[dt][2 * NH + j]);
      float po = gh[s][3 * NH + j] + bf16_to_f32(gx[dt][3 * NH + j]);
      if (t < mylen) {
        float ig = 1.f / (1.f + __expf(-pi));
        float fg = 1.f / (1.f + __expf(-pf));
        float gv = 1.f - 2.f / (1.f + __expf(2.f * pg));
        float og = 1.f / (1.f + __expf(-po));
        c = fg * c + ig * gv;
        h = og * (1.f - 2.f / (1.f + __expf(2.f * c)));
        hbuf[s][j] = f32_to_bf16(h);
      }
    }
    __syncthreads();
  }

  // ---- LayerNorm over H=256 per sequence (waves 0-3: seq0, 4-7: seq1) ----
  float sum = h, sq = h * h;
#pragma unroll
  for (int off = 32; off > 0; off >>= 1) {
    sum += __shfl_xor(sum, off);
    sq  += __shfl_xor(sq, off);
  }
  if (l == 0) { red[w] = sum; red[8 + w] = sq; }
  __syncthreads();
  if (tid == 0) {
    float S = red[0] + red[1] + red[2] + red[3];
    float Q = red[8] + red[9] + red[10] + red[11];
    float mu = S * (1.f / NH);
    red[16] = mu;
    red[17] = rsqrtf(Q * (1.f / NH) - mu * mu + EPSV);
  }
  if (tid == 256) {
    float S = red[4] + red[5] + red[6] + red[7];
    float Q = red[12] + red[13] + red[14] + red[15];
    float mu = S * (1.f / NH);
    red[18] = mu;
    red[19] = rsqrtf(Q * (1.f / NH) - mu * mu + EPSV);
  }
  __syncthreads();
  {
    float mu = red[16 + 2 * s], rstd = red[17 + 2 * s];
    int b = s ? b1 : b0;
    out[(size_t)b * NH + j] = (h - mu) * rstd * gamma[j] + beta[j];
  }
}

extern "C" void kernel_launch(void* const* d_in, const int* in_sizes, int n_in,
                              void* d_out, int out_size, void* d_ws, size_t ws_size,
                              hipStream_t stream) {
  const float* X       = (const float*)d_in[0];
  const int*   lengths = (const int*)d_in[1];
  const float* W_ih    = (const float*)d_in[2];
  const float* W_hh    = (const float*)d_in[3];
  const float* b_ih    = (const float*)d_in[4];
  const float* b_hh    = (const float*)d_in[5];
  const float* gamma   = (const float*)d_in[6];
  const float* beta    = (const float*)d_in[7];
  float* out = (float*)d_out;

  // workspace layout (768 KB weights + 4 KB bsum + 2 KB perm)
  unsigned short* Wf = (unsigned short*)d_ws;
  float* bsum = (float*)((char*)d_ws + (size_t)768 * 512 * sizeof(unsigned short));
  int* perm = (int*)((char*)bsum + NG * sizeof(float));

  int total = 768 * 512;   // (512 W_hh + 256 W_ih frags) * 512 elems
  prep_kernel<<<(total + 255) / 256, 256, 0, stream>>>(W_ih, W_hh, b_ih, b_hh, Wf, bsum);
  sort_kernel<<<1, NB, 0, stream>>>(lengths, perm);
  lstm_ln_kernel<<<NB / 2, 512, 0, stream>>>(X, lengths, perm, (const short8*)Wf, bsum,
                                             gamma, beta, out);
}